// Round 10
// baseline (249.187 us; speedup 1.0000x reference)
//
#include <hip/hip_runtime.h>

// Round-15: block-coherent 1 KB page-visits — the one structure r13 did NOT
// test.
// r14: r11 restore reproduced (83 us, FETCH 65.6 MB, WRITE 131 MB exact).
// r13 autopsy: its 1 KB-per-wave-instruction probe was queue-starved, not
// page-falsifying: 128 waves total (half the CUs empty, occ 1.3%) and 64
// outstanding VMEM/wave needed (> vmcnt 63 ceiling). So "1 KB chunks" was
// never actually tested at healthy parallelism.
// Hypothesis (fits all data): HBM pseudo-channel row ~= 1 KB; r11's 256 B
// per page-visit is activate-rate-bound at ~1/3 of achievable -> matches
// 2.4 vs 6.6 TB/s exactly.
// This kernel: 256-thread BLOCK owns a 1 KB-wide x H strip (thread = one
// float column). One block-step = 4 wave-instructions hitting the SAME 1 KB
// page-row back-to-back. 4 strips/image x 32 images = 128 blocks x 4 waves
// = 512 waves (same TLP as the 83 us r11). Per wave: 256 B/instr, D=32 deep
// (r11-proven schedulable); ~4 MB of reads in flight machine-wide.
// Zero sync, zero LDS, x once, out once, full-line stores. Risk bounded: if
// the 4 waves drift, stream decays to r11's 256 B granularity (~83 us).
// Pre-committed falsifier: dur >= 78 us -> strided cap is granularity-
// independent; restore r11 and declare roofline next round.

constexpr int B = 32;
constexpr int H = 1024;
constexpr int W = 1024;            // floats per row (4 KB)
constexpr int SWF = 256;           // strip width in floats = 1 KB
constexpr int NSTRIP = W / SWF;    // 4 strips per image
constexpr int NBLK = B * NSTRIP;   // 128 blocks (256 threads = 4 waves each)
constexpr int D = 32;              // prefetch depth in rows; MUST divide H
static_assert(H % D == 0, "D must divide H");

__global__ __launch_bounds__(256) void cummax_page(const float* __restrict__ x,
                                                   float* __restrict__ o) {
    const int sid = blockIdx.x;
    const int b = sid >> 2;             // image
    const int st = sid & (NSTRIP - 1);  // strip within row
    const int t = threadIdx.x;          // 0..255 = float column within strip

    const size_t base = (size_t)b * H * W + (size_t)st * SWF + t;
    const float* xp = x + base;
    float* op = o + base;

    float carry = -__builtin_inff();
    float buf[D];

    // prologue: prefetch rows 0..D-1
#pragma unroll
    for (int r = 0; r < D; ++r) buf[r] = xp[(size_t)r * W];

    // main: process D rows, prefetch the next D (all buf indices static)
    int hb = 0;
    for (; hb < H - D; hb += D) {
        const float* xn = xp + (size_t)(hb + D) * W;
        float* on = op + (size_t)hb * W;
#pragma unroll
        for (int r = 0; r < D; ++r) {
            float v = buf[r];
            buf[r] = xn[(size_t)r * W];       // prefetch row hb+D+r
            carry = fmaxf(carry, v);
            on[(size_t)r * W] = carry;        // store row hb+r
        }
    }

    // epilogue: last D rows (already in buf), no prefetch
    {
        float* on = op + (size_t)hb * W;
#pragma unroll
        for (int r = 0; r < D; ++r) {
            carry = fmaxf(carry, buf[r]);
            on[(size_t)r * W] = carry;
        }
    }
}

extern "C" void kernel_launch(void* const* d_in, const int* in_sizes, int n_in,
                              void* d_out, int out_size, void* d_ws, size_t ws_size,
                              hipStream_t stream) {
    const float* x = (const float*)d_in[0];
    float* out = (float*)d_out;
    cummax_page<<<NBLK, 256, 0, stream>>>(x, out);
}

// Round 11
// 235.085 us; speedup vs baseline: 1.0600x; 1.0600x over previous
//
#include <hip/hip_runtime.h>

// Round-16: FINAL restore of round-11's cummax_stream — argmin of 11
// measured structures (83.2 us dispatch / ~235 us bench, absmax 0.0,
// reproduced twice: r11, r14).
//
// Design-space map (all measured, all ideal-traffic unless noted):
//   chunk granularity (strided single-pass, no sync):
//     64 B (r6) 2.33 TB/s | 128 B (r5) 2.29 | 256 B (r11/14) 2.42 |
//     1 KB/wave (r13, queue-starved) 1.87 | 1 KB/block (r15) 2.2
//     -> ~2.4 TB/s cap is granularity-invariant; page-amortization
//        falsified at starved AND healthy parallelism.
//   linear traversal alternatives:
//     two-pass segment scan (r7/r12) ~105 us (second x pass);
//     coop grid.sync (r9) 201 us (~120 us barrier);
//     flags+spin (r8) 320 us (per-block wbL2/inv storms).
// The scan dependency forces column ownership; column ownership forces a
// 4 KB-strided temporal stream; that stream caps at ~2.4 TB/s on this chip
// regardless of every knob reachable from HIP source. 83 us = 201 MB HBM
// traffic at the pattern cap, VALUBusy 4% -> memory-pattern-bound roofline.
//
// Structure: wave owns a 256 B-wide x H strip (lane = one float column);
// 512 one-wave blocks (2/CU); buf[32] register prefetch, static indices,
// D divides H exactly; zero sync, zero LDS, x read once, out written once,
// full-line stores.

constexpr int B = 32;
constexpr int H = 1024;
constexpr int W = 1024;            // floats per row (4 KB)
constexpr int SWF = 64;            // strip width in floats = 256 B
constexpr int NSTRIP = W / SWF;    // 16 strips per image
constexpr int NBLK = B * NSTRIP;   // 512 one-wave blocks
constexpr int D = 32;              // prefetch depth in rows; MUST divide H
static_assert(H % D == 0, "D must divide H");

__global__ __launch_bounds__(64) void cummax_stream(const float* __restrict__ x,
                                                    float* __restrict__ o) {
    const int sid = blockIdx.x;
    const int b = sid >> 4;             // image
    const int st = sid & (NSTRIP - 1);  // strip within row
    const int lane = threadIdx.x;       // 0..63 = float column within strip

    const size_t base = (size_t)b * H * W + (size_t)st * SWF + lane;
    const float* xp = x + base;
    float* op = o + base;

    float carry = -__builtin_inff();
    float buf[D];

    // prologue: prefetch rows 0..D-1
#pragma unroll
    for (int r = 0; r < D; ++r) buf[r] = xp[(size_t)r * W];

    // main: process D rows, prefetch the next D (all buf indices static)
    int hb = 0;
    for (; hb < H - D; hb += D) {
        const float* xn = xp + (size_t)(hb + D) * W;
        float* on = op + (size_t)hb * W;
#pragma unroll
        for (int r = 0; r < D; ++r) {
            float v = buf[r];
            buf[r] = xn[(size_t)r * W];       // prefetch row hb+D+r
            carry = fmaxf(carry, v);
            on[(size_t)r * W] = carry;        // store row hb+r
        }
    }

    // epilogue: last D rows (already in buf), no prefetch
    {
        float* on = op + (size_t)hb * W;
#pragma unroll
        for (int r = 0; r < D; ++r) {
            carry = fmaxf(carry, buf[r]);
            on[(size_t)r * W] = carry;
        }
    }
}

extern "C" void kernel_launch(void* const* d_in, const int* in_sizes, int n_in,
                              void* d_out, int out_size, void* d_ws, size_t ws_size,
                              hipStream_t stream) {
    const float* x = (const float*)d_in[0];
    float* out = (float*)d_out;
    cummax_stream<<<NBLK, 64, 0, stream>>>(x, out);
}